// Round 11
// baseline (145.263 us; speedup 1.0000x reference)
//
#include <hip/hip_runtime.h>

#define B_ 8
#define T_ 2048
#define C_ 1024
#define H_ 64

typedef __attribute__((ext_vector_type(8))) short short8;
typedef __attribute__((ext_vector_type(4))) float floatx4;
typedef __attribute__((ext_vector_type(4))) int intx4;

static __device__ __forceinline__ unsigned short f2bf(float f) {
  unsigned int u = __builtin_bit_cast(unsigned int, f);
  u += 0x7FFFu + ((u >> 16) & 1u);   // RNE
  return (unsigned short)(u >> 16);
}
static __device__ __forceinline__ unsigned short f2bf_t(float f) {   // truncate
  return (unsigned short)(__builtin_bit_cast(unsigned int, f) >> 16);
}
static __device__ __forceinline__ float bf2f(unsigned short u) {
  return __builtin_bit_cast(float, ((unsigned int)u) << 16);
}
static __device__ __forceinline__ unsigned int fbits(float f) {
  return __builtin_bit_cast(unsigned int, f);
}

typedef const __attribute__((address_space(1))) unsigned int* gp1_t;
typedef __attribute__((address_space(3))) unsigned int* lp3_t;
static __device__ __forceinline__ void gl_lds16(const void* g, void* l) {
  __builtin_amdgcn_global_load_lds((gp1_t)g, (lp3_t)l, 16, 0, 0);
}

// ---------------------------------------------------------------------------
// Kernel 0a: x fp32 -> xb bf16 (truncate -- same numerics as the in-kernel
// perm pack qkv used through round 10). Pure streaming, 96 MB traffic.
// ---------------------------------------------------------------------------
__global__ __launch_bounds__(256) void conv_x(const float* __restrict__ x,
                                              unsigned short* __restrict__ xb) {
  size_t idx = (size_t)blockIdx.x * 256 + threadIdx.x;   // 2,097,152 threads
  const float4 f0 = *(const float4*)&x[idx * 8];
  const float4 f1 = *(const float4*)&x[idx * 8 + 4];
  intx4 pk;
  pk[0] = (int)__builtin_amdgcn_perm(fbits(f0.y), fbits(f0.x), 0x07060302u);
  pk[1] = (int)__builtin_amdgcn_perm(fbits(f0.w), fbits(f0.z), 0x07060302u);
  pk[2] = (int)__builtin_amdgcn_perm(fbits(f1.y), fbits(f1.x), 0x07060302u);
  pk[3] = (int)__builtin_amdgcn_perm(fbits(f1.w), fbits(f1.z), 0x07060302u);
  *(intx4*)&xb[idx * 8] = pk;
}

// ---------------------------------------------------------------------------
// Kernel 0b: W fp32 -> Wf FRAGMENT-READY bf16 (unchanged).
// ---------------------------------------------------------------------------
__global__ __launch_bounds__(256) void conv_w(const float* __restrict__ wq,
    const float* __restrict__ wk, const float* __restrict__ wv,
    unsigned short* __restrict__ wf) {
  int c = blockIdx.x * 256 + threadIdx.x;   // 24576 chunks
  int lane = c & 63;
  int t = c >> 6;
  int ng = t % 12;
  int kk = t / 12;                           // kt*2+ks, 0..31
  int k0 = kk * 32 + (lane >> 4) * 8;
  int n = ng * 16 + (lane & 15);
  const float* src;
  int col;
  float scale = 1.0f;
  if (n < 64)       { src = wq; col = n;       scale = 0.03125f * 1.44269504088896340736f; }
  else if (n < 128) { src = wk; col = n - 64;  }
  else              { src = wv; col = n - 128; }
  unsigned short o[8];
#pragma unroll
  for (int j = 0; j < 8; ++j) o[j] = f2bf(src[(size_t)(k0 + j) * H_ + col] * scale);
  *(uint4*)&wf[(size_t)c * 8] = *(const uint4*)o;
}

// ---------------------------------------------------------------------------
// Kernel 1: QKV projection, zero-barrier K-loop on a BF16 slab.
// Grid 1024 (16-row M-tiles), 4 waves, LDS 32 KB -> 4 blocks/CU ALL RESIDENT
// (the round-10 fp32 slab was 64 KB -> 2 blocks/CU, leaving the serialized
// per-wave W-load chain exposed; 4 waves/SIMD interleave it away).
// A-fragment = one direct ds_read_b128 (no fp32->bf16 perms in the loop).
// XOR swizzle on 16B chunks keeps unpadded LDS reads conflict-free.
// ---------------------------------------------------------------------------
__global__ __launch_bounds__(256, 4) void qkv_proj(
    const unsigned short* __restrict__ xb, const unsigned short* __restrict__ wf,
    unsigned short* __restrict__ qo, unsigned short* __restrict__ kf,
    unsigned short* __restrict__ vf) {
  __shared__ unsigned short XL[16384];   // 16 rows x 1024 bf16 = 32 KB
  int tid = threadIdx.x;
  int wave = tid >> 6, lane = tid & 63;
  int lane4 = lane & 15, quad = lane >> 4;
  int m0 = blockIdx.x * 16;

  // ---- stage the whole slab (one barrier for the entire kernel) ----
  // 2048 chunks of 16B; 128 chunks per row; XOR-swizzled within 8-groups.
#pragma unroll
  for (int j = 0; j < 8; ++j) {
    int p = (wave * 8 + j) * 64 + lane;
    int r = p >> 7, pc = p & 127;
    int cl = (pc & ~7) | ((pc ^ (r & 7)) & 7);
    gl_lds16(&xb[(size_t)(m0 + r) * C_ + cl * 8], &XL[p * 8]);
  }
  __syncthreads();

  floatx4 acc[3];
#pragma unroll
  for (int nt = 0; nt < 3; ++nt) acc[nt] = (floatx4)0.0f;

#pragma unroll 4
  for (int s = 0; s < 32; ++s) {       // ks-steps over K=1024
    short8 b[3];
#pragma unroll
    for (int nt = 0; nt < 3; ++nt)
      b[nt] = *(const short8*)&wf[(size_t)(s * 12 + wave * 3 + nt) * 512 + lane * 8];
    int r = lane4;
    int c0 = s * 4 + quad;             // 16B-chunk index within the row
    int pc = (c0 & ~7) | ((c0 ^ (r & 7)) & 7);
    short8 a = *(const short8*)&XL[r * 1024 + pc * 8];
#pragma unroll
    for (int nt = 0; nt < 3; ++nt)
      acc[nt] = __builtin_amdgcn_mfma_f32_16x16x32_bf16(a, b[nt], acc[nt], 0, 0, 0);
  }

  // ---- epilogue: q direct; K,V via LDS into fragment-ready layouts ----
  unsigned short* VTB = &XL[0];                 // [64 h][24] bf16 (V^T local)
  unsigned short* KB  = VTB + 64 * 24;          // [16 t][80] bf16
  __syncthreads();   // slab reads done before reuse
#pragma unroll
  for (int nt = 0; nt < 3; ++nt) {
    int n = wave * 48 + nt * 16 + lane4;
#pragma unroll
    for (int rr = 0; rr < 4; ++rr) {
      unsigned short val = f2bf(acc[nt][rr]);
      int lrow = quad * 4 + rr;
      if (n < 64)       qo[(size_t)(m0 + lrow) * H_ + n] = val;
      else if (n < 128) KB[lrow * 80 + (n - 64)] = val;
      else              VTB[(n - 128) * 24 + lrow] = val;
    }
  }
  __syncthreads();
  {
    int bb = m0 >> 11, t0 = m0 & 2047;
    int st = t0 >> 6;
    if (tid < 128) {
      // K: block covers ct = (t0>>4)&3; chunks (ks=0,1) x 64 lanes
      int ks = tid >> 6, ln = tid & 63;
      int ct = (t0 >> 4) & 3;
      int tl = ln & 15;
      int h0 = ks * 32 + (ln >> 4) * 8;
      uint4 kd = *(const uint4*)&KB[tl * 80 + h0];
      *(uint4*)&kf[((size_t)((bb * 32 + st) * 2 + ks) * 4 + ct) * 512 + ln * 8] = kd;
    } else {
      // V: ksv = (t0>>5)&1, quads q0,q0+1; 4 nt x 32 lanes
      int u = tid - 128;
      int nt = u >> 5, li = u & 31;
      int ksv = (t0 >> 5) & 1;
      int q0 = (t0 >> 3) & 3;
      int qq = q0 + (li >> 4), l4 = li & 15;
      uint4 vd = *(const uint4*)&VTB[(nt * 16 + l4) * 24 + (li >> 4) * 8];
      *(uint4*)&vf[((size_t)((bb * 32 + st) * 2 + ksv) * 4 + nt) * 512 + (qq * 16 + l4) * 8] = vd;
    }
  }
}

// ---------------------------------------------------------------------------
// Kernel 2: causal flash attention, barrier-free, split-4, fixed-max softmax
// (m=8, base-2 scale folded into Wq). Unchanged from round 7.
// ---------------------------------------------------------------------------
__global__ __launch_bounds__(256) void attn(
    const unsigned short* __restrict__ qi, const unsigned short* __restrict__ Kf,
    const unsigned short* __restrict__ Vf, unsigned short* __restrict__ Op,
    float* __restrict__ lsum) {
  __shared__ unsigned short PL[4][16][72];

  int tid = threadIdx.x;
  int wave = tid >> 6, lane = tid & 63;
  int lane4 = lane & 15, quad = lane >> 4;
  int qt = 31 - (int)blockIdx.x;   // biggest blocks dispatch first
  int b = blockIdx.y, split = blockIdx.z;
  int qb = qt * 64;
  int base = b * T_;

  int ntile = qt + 1;
  int sBeg = (split * ntile) >> 2;
  int sEnd = ((split + 1) * ntile) >> 2;

  short8 aq[2];
#pragma unroll
  for (int ks = 0; ks < 2; ++ks)
    aq[ks] = *(const short8*)&qi[(size_t)(base + qb + wave * 16 + lane4) * H_ + ks * 32 + quad * 8];

  float lrow[4];
  floatx4 o[4];
#pragma unroll
  for (int r = 0; r < 4; ++r) lrow[r] = 0.0f;
#pragma unroll
  for (int nt = 0; nt < 4; ++nt) o[nt] = (floatx4)0.0f;

  for (int st = sBeg; st < sEnd; ++st) {
    size_t tb = (size_t)(b * 32 + st) * 8;
    short8 bk[2][4], bv[2][4];
#pragma unroll
    for (int ks = 0; ks < 2; ++ks)
#pragma unroll
      for (int ct = 0; ct < 4; ++ct)
        bk[ks][ct] = *(const short8*)&Kf[(tb + ks * 4 + ct) * 512 + lane * 8];
#pragma unroll
    for (int ks = 0; ks < 2; ++ks)
#pragma unroll
      for (int nt = 0; nt < 4; ++nt)
        bv[ks][nt] = *(const short8*)&Vf[(tb + ks * 4 + nt) * 512 + lane * 8];

    floatx4 sacc[4];
#pragma unroll
    for (int ct = 0; ct < 4; ++ct) sacc[ct] = (floatx4)0.0f;
#pragma unroll
    for (int ks = 0; ks < 2; ++ks)
#pragma unroll
      for (int ct = 0; ct < 4; ++ct)
        sacc[ct] = __builtin_amdgcn_mfma_f32_16x16x32_bf16(aq[ks], bk[ks][ct], sacc[ct], 0, 0, 0);

    if (st == qt) {   // diagonal tile mask
#pragma unroll
      for (int ct = 0; ct < 4; ++ct)
#pragma unroll
        for (int r = 0; r < 4; ++r) {
          int qrow = wave * 16 + quad * 4 + r;
          int scol = ct * 16 + lane4;
          if (scol > qrow) sacc[ct][r] = -3.0e38f;
        }
    }

    // fixed-max softmax: p = exp2(s - 8)
#pragma unroll
    for (int ct = 0; ct < 4; ++ct)
#pragma unroll
      for (int r = 0; r < 4; ++r) {
        float p = exp2f(sacc[ct][r] - 8.0f);
        lrow[r] += p;
        PL[wave][quad * 4 + r][ct * 16 + lane4] = f2bf_t(p);
      }

    // O += P V  (PL write->read same-wave; lgkmcnt orders it)
#pragma unroll
    for (int ks = 0; ks < 2; ++ks) {
      short8 pa = *(const short8*)&PL[wave][lane4][ks * 32 + quad * 8];
#pragma unroll
      for (int nt = 0; nt < 4; ++nt)
        o[nt] = __builtin_amdgcn_mfma_f32_16x16x32_bf16(pa, bv[ks][nt], o[nt], 0, 0, 0);
    }
  }

  // epilogue: l-reduce across the 16 lanes of each quad-group
#pragma unroll
  for (int off = 1; off < 16; off <<= 1)
#pragma unroll
    for (int r = 0; r < 4; ++r) lrow[r] += __shfl_xor(lrow[r], off);

  size_t pbase = (((size_t)split * 8 + b) * 32 + qt) * 64;
#pragma unroll
  for (int r = 0; r < 4; ++r) {
    int row = wave * 16 + quad * 4 + r;
#pragma unroll
    for (int nt = 0; nt < 4; ++nt)
      Op[(pbase + row) * 64 + nt * 16 + lane4] = f2bf(o[nt][r]);
    if (lane4 == 0) lsum[pbase + row] = lrow[r];
  }
}

// ---------------------------------------------------------------------------
// Kernel 3: merge the 4 key-range splits: out = sum(O_i) / sum(l_i).
// ---------------------------------------------------------------------------
__global__ __launch_bounds__(256) void merge_splits(
    const unsigned short* __restrict__ Op, const float* __restrict__ lsum,
    float* __restrict__ out) {
  int idx = blockIdx.x * 256 + threadIdx.x;
  int row = idx >> 4;
  int h4 = (idx & 15) * 4;
  int b = row >> 11, t = row & 2047;
  int qt = t >> 6, r = t & 63;
  float O0 = 0.f, O1 = 0.f, O2 = 0.f, O3 = 0.f, l = 0.f;
#pragma unroll
  for (int s = 0; s < 4; ++s) {
    size_t p = (((size_t)s * 8 + b) * 32 + qt) * 64 + r;
    l += lsum[p];
    ushort4 ov = *(const ushort4*)&Op[p * 64 + h4];
    O0 += bf2f(ov.x); O1 += bf2f(ov.y); O2 += bf2f(ov.z); O3 += bf2f(ov.w);
  }
  float inv = 1.0f / l;
  float4 res = make_float4(O0 * inv, O1 * inv, O2 * inv, O3 * inv);
  *(float4*)&out[(size_t)row * H_ + h4] = res;
}

extern "C" void kernel_launch(void* const* d_in, const int* in_sizes, int n_in,
                              void* d_out, int out_size, void* d_ws, size_t ws_size,
                              hipStream_t stream) {
  const float* x  = (const float*)d_in[0];
  const float* wq = (const float*)d_in[1];
  const float* wk = (const float*)d_in[2];
  const float* wv = (const float*)d_in[3];
  float* out = (float*)d_out;

  char* ws = (char*)d_ws;
  unsigned short* wf = (unsigned short*)ws;                    // 393216 B
  unsigned short* qb = (unsigned short*)(ws + 393216);         // 2097152 B
  unsigned short* kf = (unsigned short*)(ws + 2490368);        // 2097152 B (frag-ready)
  unsigned short* vf = (unsigned short*)(ws + 4587520);        // 2097152 B (frag-ready)
  unsigned short* Op = (unsigned short*)(ws + 6684672);        // 8388608 B (4 splits)
  float*          ls = (float*)(ws + 15073280);                // 262144 B
  unsigned short* xb = (unsigned short*)(ws + 15335424);       // 33554432 B (total 48889856)

  conv_w<<<96, 256, 0, stream>>>(wq, wk, wv, wf);
  conv_x<<<8192, 256, 0, stream>>>(x, xb);
  qkv_proj<<<1024, 256, 0, stream>>>(xb, wf, qb, kf, vf);
  attn<<<dim3(32, 8, 4), 256, 0, stream>>>(qb, kf, vf, Op, ls);
  merge_splits<<<1024, 256, 0, stream>>>(Op, ls, out);
}

// Round 12
// 138.037 us; speedup vs baseline: 1.0523x; 1.0523x over previous
//
#include <hip/hip_runtime.h>

#define B_ 8
#define T_ 2048
#define C_ 1024
#define H_ 64

typedef __attribute__((ext_vector_type(8))) short short8;
typedef __attribute__((ext_vector_type(4))) float floatx4;
typedef __attribute__((ext_vector_type(4))) int intx4;

static __device__ __forceinline__ unsigned short f2bf(float f) {
  unsigned int u = __builtin_bit_cast(unsigned int, f);
  u += 0x7FFFu + ((u >> 16) & 1u);   // RNE
  return (unsigned short)(u >> 16);
}
static __device__ __forceinline__ unsigned short f2bf_t(float f) {   // truncate
  return (unsigned short)(__builtin_bit_cast(unsigned int, f) >> 16);
}
static __device__ __forceinline__ float bf2f(unsigned short u) {
  return __builtin_bit_cast(float, ((unsigned int)u) << 16);
}
static __device__ __forceinline__ unsigned int fbits(float f) {
  return __builtin_bit_cast(unsigned int, f);
}

typedef const __attribute__((address_space(1))) unsigned int* gp1_t;
typedef __attribute__((address_space(3))) unsigned int* lp3_t;
static __device__ __forceinline__ void gl_lds16(const void* g, void* l) {
  __builtin_amdgcn_global_load_lds((gp1_t)g, (lp3_t)l, 16, 0, 0);
}

// ---------------------------------------------------------------------------
// Kernel 0: W fp32 -> Wf FRAGMENT-READY bf16 (unchanged).
// ---------------------------------------------------------------------------
__global__ __launch_bounds__(256) void conv_w(const float* __restrict__ wq,
    const float* __restrict__ wk, const float* __restrict__ wv,
    unsigned short* __restrict__ wf) {
  int c = blockIdx.x * 256 + threadIdx.x;   // 24576 chunks
  int lane = c & 63;
  int t = c >> 6;
  int ng = t % 12;
  int kk = t / 12;                           // kt*2+ks, 0..31
  int k0 = kk * 32 + (lane >> 4) * 8;
  int n = ng * 16 + (lane & 15);
  const float* src;
  int col;
  float scale = 1.0f;
  if (n < 64)       { src = wq; col = n;       scale = 0.03125f * 1.44269504088896340736f; }
  else if (n < 128) { src = wk; col = n - 64;  }
  else              { src = wv; col = n - 128; }
  unsigned short o[8];
#pragma unroll
  for (int j = 0; j < 8; ++j) o[j] = f2bf(src[(size_t)(k0 + j) * H_ + col] * scale);
  *(uint4*)&wf[(size_t)c * 8] = *(const uint4*)o;
}

// ---------------------------------------------------------------------------
// Kernel 1: QKV projection, TWO-PHASE fp32 staging, 32 KB LDS -> 4 blocks/CU.
// Grid 1024 (16-row M-tiles), 4 waves. Round-11 lesson: the bf16 pre-convert
// kernel bought 4 blocks/CU but cost a 96 MB x round-trip; instead stage x
// fp32 in two 16x512 half-slabs into the SAME 32 KB buffer (3 barriers
// total), converting to bf16 at fragment-read with v_perm (truncate).
// W: direct frag loads from Wf (L2-resident 1 KB bursts); the serialized
// W-load chain is hidden by 4 waves/SIMD of TLP (round-11 evidence).
// XOR swizzle on 16B source chunks keeps unpadded LDS reads conflict-free.
// ---------------------------------------------------------------------------
__global__ __launch_bounds__(256, 4) void qkv_proj(
    const float* __restrict__ x, const unsigned short* __restrict__ wf,
    unsigned short* __restrict__ qo, unsigned short* __restrict__ kf,
    unsigned short* __restrict__ vf) {
  __shared__ float XL[8192];   // 16 rows x 512 fp32 = 32 KB (one K-half)
  int tid = threadIdx.x;
  int wave = tid >> 6, lane = tid & 63;
  int lane4 = lane & 15, quad = lane >> 4;
  int m0 = blockIdx.x * 16;

  // stage one K-half (16 rows x 512 floats): 2048 16B-chunks, 8 insts/thread
  auto stage_half = [&](int ph) {
#pragma unroll
    for (int j = 0; j < 8; ++j) {
      int c = (wave * 8 + j) * 64 + lane;    // chunk id 0..2047
      int r = c >> 7, pc = c & 127;
      int cl = (pc & ~7) | ((pc ^ (r & 7)) & 7);
      gl_lds16(&x[(size_t)(m0 + r) * C_ + ph * 512 + cl * 4], &XL[c * 4]);
    }
  };

  floatx4 acc[3];
#pragma unroll
  for (int nt = 0; nt < 3; ++nt) acc[nt] = (floatx4)0.0f;

  stage_half(0);
  __syncthreads();

  for (int ph = 0; ph < 2; ++ph) {
    if (ph) {
      __syncthreads();      // all phase-0 reads done before overwrite
      stage_half(1);
      __syncthreads();      // phase-1 data visible
    }
#pragma unroll 4
    for (int sl = 0; sl < 16; ++sl) {
      int s = ph * 16 + sl;          // global ks-step, 0..31
      short8 b[3];
#pragma unroll
      for (int nt = 0; nt < 3; ++nt)
        b[nt] = *(const short8*)&wf[(size_t)(s * 12 + wave * 3 + nt) * 512 + lane * 8];
      int r = lane4;
      int c0 = sl * 8 + quad * 2;    // float4-chunk in the 128-chunk row
      int pc0 = (c0 & ~7) | ((c0 ^ (r & 7)) & 7);
      int pc1 = ((c0 + 1) & ~7) | (((c0 + 1) ^ (r & 7)) & 7);
      float4 f0 = *(const float4*)&XL[r * 512 + pc0 * 4];
      float4 f1 = *(const float4*)&XL[r * 512 + pc1 * 4];
      intx4 pk;
      pk[0] = (int)__builtin_amdgcn_perm(fbits(f0.y), fbits(f0.x), 0x07060302u);
      pk[1] = (int)__builtin_amdgcn_perm(fbits(f0.w), fbits(f0.z), 0x07060302u);
      pk[2] = (int)__builtin_amdgcn_perm(fbits(f1.y), fbits(f1.x), 0x07060302u);
      pk[3] = (int)__builtin_amdgcn_perm(fbits(f1.w), fbits(f1.z), 0x07060302u);
      short8 a = __builtin_bit_cast(short8, pk);
#pragma unroll
      for (int nt = 0; nt < 3; ++nt)
        acc[nt] = __builtin_amdgcn_mfma_f32_16x16x32_bf16(a, b[nt], acc[nt], 0, 0, 0);
    }
  }

  // ---- epilogue: q direct; K,V via LDS into fragment-ready layouts ----
  unsigned short* VTB = (unsigned short*)&XL[0];   // [64 h][24] bf16 (V^T local)
  unsigned short* KB  = VTB + 64 * 24;             // [16 t][80] bf16
  __syncthreads();   // slab reads done before reuse
#pragma unroll
  for (int nt = 0; nt < 3; ++nt) {
    int n = wave * 48 + nt * 16 + lane4;
#pragma unroll
    for (int rr = 0; rr < 4; ++rr) {
      unsigned short val = f2bf(acc[nt][rr]);
      int lrow = quad * 4 + rr;
      if (n < 64)       qo[(size_t)(m0 + lrow) * H_ + n] = val;
      else if (n < 128) KB[lrow * 80 + (n - 64)] = val;
      else              VTB[(n - 128) * 24 + lrow] = val;
    }
  }
  __syncthreads();
  {
    int bb = m0 >> 11, t0 = m0 & 2047;
    int st = t0 >> 6;
    if (tid < 128) {
      // K: block covers ct = (t0>>4)&3; chunks (ks=0,1) x 64 lanes
      int ks = tid >> 6, ln = tid & 63;
      int ct = (t0 >> 4) & 3;
      int tl = ln & 15;
      int h0 = ks * 32 + (ln >> 4) * 8;
      uint4 kd = *(const uint4*)&KB[tl * 80 + h0];
      *(uint4*)&kf[((size_t)((bb * 32 + st) * 2 + ks) * 4 + ct) * 512 + ln * 8] = kd;
    } else {
      // V: ksv = (t0>>5)&1, quads q0,q0+1; 4 nt x 32 lanes
      int u = tid - 128;
      int nt = u >> 5, li = u & 31;
      int ksv = (t0 >> 5) & 1;
      int q0 = (t0 >> 3) & 3;
      int qq = q0 + (li >> 4), l4 = li & 15;
      uint4 vd = *(const uint4*)&VTB[(nt * 16 + l4) * 24 + (li >> 4) * 8];
      *(uint4*)&vf[((size_t)((bb * 32 + st) * 2 + ksv) * 4 + nt) * 512 + (qq * 16 + l4) * 8] = vd;
    }
  }
}

// ---------------------------------------------------------------------------
// Kernel 2: causal flash attention, barrier-free, split-4, fixed-max softmax
// (m=8, base-2 scale folded into Wq). Unchanged from round 7.
// ---------------------------------------------------------------------------
__global__ __launch_bounds__(256) void attn(
    const unsigned short* __restrict__ qi, const unsigned short* __restrict__ Kf,
    const unsigned short* __restrict__ Vf, unsigned short* __restrict__ Op,
    float* __restrict__ lsum) {
  __shared__ unsigned short PL[4][16][72];

  int tid = threadIdx.x;
  int wave = tid >> 6, lane = tid & 63;
  int lane4 = lane & 15, quad = lane >> 4;
  int qt = 31 - (int)blockIdx.x;   // biggest blocks dispatch first
  int b = blockIdx.y, split = blockIdx.z;
  int qb = qt * 64;
  int base = b * T_;

  int ntile = qt + 1;
  int sBeg = (split * ntile) >> 2;
  int sEnd = ((split + 1) * ntile) >> 2;

  short8 aq[2];
#pragma unroll
  for (int ks = 0; ks < 2; ++ks)
    aq[ks] = *(const short8*)&qi[(size_t)(base + qb + wave * 16 + lane4) * H_ + ks * 32 + quad * 8];

  float lrow[4];
  floatx4 o[4];
#pragma unroll
  for (int r = 0; r < 4; ++r) lrow[r] = 0.0f;
#pragma unroll
  for (int nt = 0; nt < 4; ++nt) o[nt] = (floatx4)0.0f;

  for (int st = sBeg; st < sEnd; ++st) {
    size_t tb = (size_t)(b * 32 + st) * 8;
    short8 bk[2][4], bv[2][4];
#pragma unroll
    for (int ks = 0; ks < 2; ++ks)
#pragma unroll
      for (int ct = 0; ct < 4; ++ct)
        bk[ks][ct] = *(const short8*)&Kf[(tb + ks * 4 + ct) * 512 + lane * 8];
#pragma unroll
    for (int ks = 0; ks < 2; ++ks)
#pragma unroll
      for (int nt = 0; nt < 4; ++nt)
        bv[ks][nt] = *(const short8*)&Vf[(tb + ks * 4 + nt) * 512 + lane * 8];

    floatx4 sacc[4];
#pragma unroll
    for (int ct = 0; ct < 4; ++ct) sacc[ct] = (floatx4)0.0f;
#pragma unroll
    for (int ks = 0; ks < 2; ++ks)
#pragma unroll
      for (int ct = 0; ct < 4; ++ct)
        sacc[ct] = __builtin_amdgcn_mfma_f32_16x16x32_bf16(aq[ks], bk[ks][ct], sacc[ct], 0, 0, 0);

    if (st == qt) {   // diagonal tile mask
#pragma unroll
      for (int ct = 0; ct < 4; ++ct)
#pragma unroll
        for (int r = 0; r < 4; ++r) {
          int qrow = wave * 16 + quad * 4 + r;
          int scol = ct * 16 + lane4;
          if (scol > qrow) sacc[ct][r] = -3.0e38f;
        }
    }

    // fixed-max softmax: p = exp2(s - 8)
#pragma unroll
    for (int ct = 0; ct < 4; ++ct)
#pragma unroll
      for (int r = 0; r < 4; ++r) {
        float p = exp2f(sacc[ct][r] - 8.0f);
        lrow[r] += p;
        PL[wave][quad * 4 + r][ct * 16 + lane4] = f2bf_t(p);
      }

    // O += P V  (PL write->read same-wave; lgkmcnt orders it)
#pragma unroll
    for (int ks = 0; ks < 2; ++ks) {
      short8 pa = *(const short8*)&PL[wave][lane4][ks * 32 + quad * 8];
#pragma unroll
      for (int nt = 0; nt < 4; ++nt)
        o[nt] = __builtin_amdgcn_mfma_f32_16x16x32_bf16(pa, bv[ks][nt], o[nt], 0, 0, 0);
    }
  }

  // epilogue: l-reduce across the 16 lanes of each quad-group
#pragma unroll
  for (int off = 1; off < 16; off <<= 1)
#pragma unroll
    for (int r = 0; r < 4; ++r) lrow[r] += __shfl_xor(lrow[r], off);

  size_t pbase = (((size_t)split * 8 + b) * 32 + qt) * 64;
#pragma unroll
  for (int r = 0; r < 4; ++r) {
    int row = wave * 16 + quad * 4 + r;
#pragma unroll
    for (int nt = 0; nt < 4; ++nt)
      Op[(pbase + row) * 64 + nt * 16 + lane4] = f2bf(o[nt][r]);
    if (lane4 == 0) lsum[pbase + row] = lrow[r];
  }
}

// ---------------------------------------------------------------------------
// Kernel 3: merge the 4 key-range splits: out = sum(O_i) / sum(l_i).
// ---------------------------------------------------------------------------
__global__ __launch_bounds__(256) void merge_splits(
    const unsigned short* __restrict__ Op, const float* __restrict__ lsum,
    float* __restrict__ out) {
  int idx = blockIdx.x * 256 + threadIdx.x;
  int row = idx >> 4;
  int h4 = (idx & 15) * 4;
  int b = row >> 11, t = row & 2047;
  int qt = t >> 6, r = t & 63;
  float O0 = 0.f, O1 = 0.f, O2 = 0.f, O3 = 0.f, l = 0.f;
#pragma unroll
  for (int s = 0; s < 4; ++s) {
    size_t p = (((size_t)s * 8 + b) * 32 + qt) * 64 + r;
    l += lsum[p];
    ushort4 ov = *(const ushort4*)&Op[p * 64 + h4];
    O0 += bf2f(ov.x); O1 += bf2f(ov.y); O2 += bf2f(ov.z); O3 += bf2f(ov.w);
  }
  float inv = 1.0f / l;
  float4 res = make_float4(O0 * inv, O1 * inv, O2 * inv, O3 * inv);
  *(float4*)&out[(size_t)row * H_ + h4] = res;
}

extern "C" void kernel_launch(void* const* d_in, const int* in_sizes, int n_in,
                              void* d_out, int out_size, void* d_ws, size_t ws_size,
                              hipStream_t stream) {
  const float* x  = (const float*)d_in[0];
  const float* wq = (const float*)d_in[1];
  const float* wk = (const float*)d_in[2];
  const float* wv = (const float*)d_in[3];
  float* out = (float*)d_out;

  char* ws = (char*)d_ws;
  unsigned short* wf = (unsigned short*)ws;                    // 393216 B
  unsigned short* qb = (unsigned short*)(ws + 393216);         // 2097152 B
  unsigned short* kf = (unsigned short*)(ws + 2490368);        // 2097152 B (frag-ready)
  unsigned short* vf = (unsigned short*)(ws + 4587520);        // 2097152 B (frag-ready)
  unsigned short* Op = (unsigned short*)(ws + 6684672);        // 8388608 B (4 splits)
  float*          ls = (float*)(ws + 15073280);                // 262144 B (total 15335424)

  conv_w<<<96, 256, 0, stream>>>(wq, wk, wv, wf);
  qkv_proj<<<1024, 256, 0, stream>>>(x, wf, qb, kf, vf);
  attn<<<dim3(32, 8, 4), 256, 0, stream>>>(qb, kf, vf, Op, ls);
  merge_splits<<<1024, 256, 0, stream>>>(Op, ls, out);
}

// Round 13
// 132.716 us; speedup vs baseline: 1.0945x; 1.0401x over previous
//
#include <hip/hip_runtime.h>

#define B_ 8
#define T_ 2048
#define C_ 1024
#define H_ 64

typedef __attribute__((ext_vector_type(8))) short short8;
typedef __attribute__((ext_vector_type(4))) float floatx4;
typedef __attribute__((ext_vector_type(4))) int intx4;

static __device__ __forceinline__ unsigned short f2bf(float f) {
  unsigned int u = __builtin_bit_cast(unsigned int, f);
  u += 0x7FFFu + ((u >> 16) & 1u);   // RNE
  return (unsigned short)(u >> 16);
}
static __device__ __forceinline__ unsigned short f2bf_t(float f) {   // truncate
  return (unsigned short)(__builtin_bit_cast(unsigned int, f) >> 16);
}
static __device__ __forceinline__ float bf2f(unsigned short u) {
  return __builtin_bit_cast(float, ((unsigned int)u) << 16);
}
static __device__ __forceinline__ unsigned int fbits(float f) {
  return __builtin_bit_cast(unsigned int, f);
}

typedef const __attribute__((address_space(1))) unsigned int* gp1_t;
typedef __attribute__((address_space(3))) unsigned int* lp3_t;
static __device__ __forceinline__ void gl_lds16(const void* g, void* l) {
  __builtin_amdgcn_global_load_lds((gp1_t)g, (lp3_t)l, 16, 0, 0);
}

// ---------------------------------------------------------------------------
// Kernel 0: W fp32 -> Wf FRAGMENT-READY bf16 (unchanged).
// ---------------------------------------------------------------------------
__global__ __launch_bounds__(256) void conv_w(const float* __restrict__ wq,
    const float* __restrict__ wk, const float* __restrict__ wv,
    unsigned short* __restrict__ wf) {
  int c = blockIdx.x * 256 + threadIdx.x;   // 24576 chunks
  int lane = c & 63;
  int t = c >> 6;
  int ng = t % 12;
  int kk = t / 12;                           // kt*2+ks, 0..31
  int k0 = kk * 32 + (lane >> 4) * 8;
  int n = ng * 16 + (lane & 15);
  const float* src;
  int col;
  float scale = 1.0f;
  if (n < 64)       { src = wq; col = n;       scale = 0.03125f * 1.44269504088896340736f; }
  else if (n < 128) { src = wk; col = n - 64;  }
  else              { src = wv; col = n - 128; }
  unsigned short o[8];
#pragma unroll
  for (int j = 0; j < 8; ++j) o[j] = f2bf(src[(size_t)(k0 + j) * H_ + col] * scale);
  *(uint4*)&wf[(size_t)c * 8] = *(const uint4*)o;
}

// ---------------------------------------------------------------------------
// Kernel 1: QKV projection, M=32 / 4-PHASE fp32 staging.
// Grid 512 (32-row tiles), 4 waves, 32 KB LDS -> 4 blocks/CU.
// R12 ledger: grid-1024 variants pay 1024 x 384 KB = 393 MB of Wf L2
// re-reads (~11+ us). M=32 halves that to 196 MB AND gives each W-load
// 2x MFMA work (acc[2][3] share b[3]). x staged fp32 in four 32x256
// half-slabs into one 32 KB buffer (no conv_x round-trip); bf16 convert
// at fragment-read via v_perm (truncate). XOR swizzle keeps unpadded LDS
// reads conflict-free. Epilogue = round-7 verified 32-row frag-ready K/V.
// ---------------------------------------------------------------------------
__global__ __launch_bounds__(256, 4) void qkv_proj(
    const float* __restrict__ x, const unsigned short* __restrict__ wf,
    unsigned short* __restrict__ qo, unsigned short* __restrict__ kf,
    unsigned short* __restrict__ vf) {
  __shared__ float XL[8192];   // 32 rows x 256 fp32 = 32 KB (one K-quarter)
  int tid = threadIdx.x;
  int wave = tid >> 6, lane = tid & 63;
  int lane4 = lane & 15, quad = lane >> 4;
  int m0 = blockIdx.x * 32;

  // stage one K-quarter (32 rows x 256 floats): 2048 16B-chunks, 8/thread
  auto stage_q = [&](int ph) {
#pragma unroll
    for (int j = 0; j < 8; ++j) {
      int c = (wave * 8 + j) * 64 + lane;    // chunk id 0..2047
      int r = c >> 6, pc = c & 63;           // 64 chunks per row
      int cl = (pc & ~7) | ((pc ^ (r & 7)) & 7);
      gl_lds16(&x[(size_t)(m0 + r) * C_ + ph * 256 + cl * 4], &XL[c * 4]);
    }
  };

  floatx4 acc[2][3];
#pragma unroll
  for (int mt = 0; mt < 2; ++mt)
#pragma unroll
    for (int nt = 0; nt < 3; ++nt) acc[mt][nt] = (floatx4)0.0f;

  stage_q(0);
  __syncthreads();

  for (int ph = 0; ph < 4; ++ph) {
    if (ph) {
      __syncthreads();      // all prior-phase reads done before overwrite
      stage_q(ph);
      __syncthreads();      // new phase visible
    }
#pragma unroll
    for (int sl = 0; sl < 8; ++sl) {
      int s = ph * 8 + sl;             // global ks-step, 0..31
      short8 b[3];
#pragma unroll
      for (int nt = 0; nt < 3; ++nt)
        b[nt] = *(const short8*)&wf[(size_t)(s * 12 + wave * 3 + nt) * 512 + lane * 8];
      short8 a[2];
#pragma unroll
      for (int mt = 0; mt < 2; ++mt) {
        int r = mt * 16 + lane4;
        int c0 = sl * 8 + quad * 2;    // phase-local float4-chunk, 0..63
        int pc0 = (c0 & ~7) | ((c0 ^ (r & 7)) & 7);
        int pc1 = ((c0 + 1) & ~7) | (((c0 + 1) ^ (r & 7)) & 7);
        float4 f0 = *(const float4*)&XL[r * 256 + pc0 * 4];
        float4 f1 = *(const float4*)&XL[r * 256 + pc1 * 4];
        intx4 pk;
        pk[0] = (int)__builtin_amdgcn_perm(fbits(f0.y), fbits(f0.x), 0x07060302u);
        pk[1] = (int)__builtin_amdgcn_perm(fbits(f0.w), fbits(f0.z), 0x07060302u);
        pk[2] = (int)__builtin_amdgcn_perm(fbits(f1.y), fbits(f1.x), 0x07060302u);
        pk[3] = (int)__builtin_amdgcn_perm(fbits(f1.w), fbits(f1.z), 0x07060302u);
        a[mt] = __builtin_bit_cast(short8, pk);
      }
#pragma unroll
      for (int mt = 0; mt < 2; ++mt)
#pragma unroll
        for (int nt = 0; nt < 3; ++nt)
          acc[mt][nt] = __builtin_amdgcn_mfma_f32_16x16x32_bf16(a[mt], b[nt], acc[mt][nt], 0, 0, 0);
    }
  }

  // ---- epilogue: q direct; K,V via LDS into fragment-ready layouts ----
  unsigned short* VTB = (unsigned short*)&XL[0];   // [64 h][40] bf16 (V^T local)
  unsigned short* KB  = VTB + 5120;                // [32 t][72] bf16
  __syncthreads();   // slab reads done before reuse
#pragma unroll
  for (int mt = 0; mt < 2; ++mt)
#pragma unroll
    for (int nt = 0; nt < 3; ++nt) {
      int n = wave * 48 + nt * 16 + lane4;
#pragma unroll
      for (int rr = 0; rr < 4; ++rr) {
        unsigned short val = f2bf(acc[mt][nt][rr]);
        int lrow = mt * 16 + quad * 4 + rr;
        if (n < 64)       qo[(size_t)(m0 + lrow) * H_ + n] = val;
        else if (n < 128) KB[lrow * 72 + (n - 64)] = val;
        else              VTB[(n - 128) * 40 + lrow] = val;
      }
    }
  __syncthreads();
  {
    int bb = m0 >> 11, t0 = m0 & 2047;
    int st = t0 >> 6, off = t0 & 63;
    // K: 256 chunks (ks x ctl x 64 lanes)
    int ks = tid >> 7, ctl = (tid >> 6) & 1, ln = tid & 63;
    int ct = (off >> 4) + ctl;
    int tl = ctl * 16 + (ln & 15);
    int h0 = ks * 32 + (ln >> 4) * 8;
    uint4 kd = *(const uint4*)&KB[tl * 72 + h0];
    *(uint4*)&kf[((size_t)((bb * 32 + st) * 2 + ks) * 4 + ct) * 512 + ln * 8] = kd;
    // V: 256 chunks (nt x 64 lanes), ks fixed = off>>5
    int nt = tid >> 6, l4 = tid & 15, qs = (tid >> 4) & 3;
    int ksv = off >> 5;
    uint4 vd = *(const uint4*)&VTB[(nt * 16 + l4) * 40 + qs * 8];
    *(uint4*)&vf[((size_t)((bb * 32 + st) * 2 + ksv) * 4 + nt) * 512 + (tid & 63) * 8] = vd;
  }
}

// ---------------------------------------------------------------------------
// Kernel 2: causal flash attention, barrier-free, split-4, fixed-max softmax
// (m=8, base-2 scale folded into Wq). Unchanged from round 7.
// ---------------------------------------------------------------------------
__global__ __launch_bounds__(256) void attn(
    const unsigned short* __restrict__ qi, const unsigned short* __restrict__ Kf,
    const unsigned short* __restrict__ Vf, unsigned short* __restrict__ Op,
    float* __restrict__ lsum) {
  __shared__ unsigned short PL[4][16][72];

  int tid = threadIdx.x;
  int wave = tid >> 6, lane = tid & 63;
  int lane4 = lane & 15, quad = lane >> 4;
  int qt = 31 - (int)blockIdx.x;   // biggest blocks dispatch first
  int b = blockIdx.y, split = blockIdx.z;
  int qb = qt * 64;
  int base = b * T_;

  int ntile = qt + 1;
  int sBeg = (split * ntile) >> 2;
  int sEnd = ((split + 1) * ntile) >> 2;

  short8 aq[2];
#pragma unroll
  for (int ks = 0; ks < 2; ++ks)
    aq[ks] = *(const short8*)&qi[(size_t)(base + qb + wave * 16 + lane4) * H_ + ks * 32 + quad * 8];

  float lrow[4];
  floatx4 o[4];
#pragma unroll
  for (int r = 0; r < 4; ++r) lrow[r] = 0.0f;
#pragma unroll
  for (int nt = 0; nt < 4; ++nt) o[nt] = (floatx4)0.0f;

  for (int st = sBeg; st < sEnd; ++st) {
    size_t tb = (size_t)(b * 32 + st) * 8;
    short8 bk[2][4], bv[2][4];
#pragma unroll
    for (int ks = 0; ks < 2; ++ks)
#pragma unroll
      for (int ct = 0; ct < 4; ++ct)
        bk[ks][ct] = *(const short8*)&Kf[(tb + ks * 4 + ct) * 512 + lane * 8];
#pragma unroll
    for (int ks = 0; ks < 2; ++ks)
#pragma unroll
      for (int nt = 0; nt < 4; ++nt)
        bv[ks][nt] = *(const short8*)&Vf[(tb + ks * 4 + nt) * 512 + lane * 8];

    floatx4 sacc[4];
#pragma unroll
    for (int ct = 0; ct < 4; ++ct) sacc[ct] = (floatx4)0.0f;
#pragma unroll
    for (int ks = 0; ks < 2; ++ks)
#pragma unroll
      for (int ct = 0; ct < 4; ++ct)
        sacc[ct] = __builtin_amdgcn_mfma_f32_16x16x32_bf16(aq[ks], bk[ks][ct], sacc[ct], 0, 0, 0);

    if (st == qt) {   // diagonal tile mask
#pragma unroll
      for (int ct = 0; ct < 4; ++ct)
#pragma unroll
        for (int r = 0; r < 4; ++r) {
          int qrow = wave * 16 + quad * 4 + r;
          int scol = ct * 16 + lane4;
          if (scol > qrow) sacc[ct][r] = -3.0e38f;
        }
    }

    // fixed-max softmax: p = exp2(s - 8)
#pragma unroll
    for (int ct = 0; ct < 4; ++ct)
#pragma unroll
      for (int r = 0; r < 4; ++r) {
        float p = exp2f(sacc[ct][r] - 8.0f);
        lrow[r] += p;
        PL[wave][quad * 4 + r][ct * 16 + lane4] = f2bf_t(p);
      }

    // O += P V  (PL write->read same-wave; lgkmcnt orders it)
#pragma unroll
    for (int ks = 0; ks < 2; ++ks) {
      short8 pa = *(const short8*)&PL[wave][lane4][ks * 32 + quad * 8];
#pragma unroll
      for (int nt = 0; nt < 4; ++nt)
        o[nt] = __builtin_amdgcn_mfma_f32_16x16x32_bf16(pa, bv[ks][nt], o[nt], 0, 0, 0);
    }
  }

  // epilogue: l-reduce across the 16 lanes of each quad-group
#pragma unroll
  for (int off = 1; off < 16; off <<= 1)
#pragma unroll
    for (int r = 0; r < 4; ++r) lrow[r] += __shfl_xor(lrow[r], off);

  size_t pbase = (((size_t)split * 8 + b) * 32 + qt) * 64;
#pragma unroll
  for (int r = 0; r < 4; ++r) {
    int row = wave * 16 + quad * 4 + r;
#pragma unroll
    for (int nt = 0; nt < 4; ++nt)
      Op[(pbase + row) * 64 + nt * 16 + lane4] = f2bf(o[nt][r]);
    if (lane4 == 0) lsum[pbase + row] = lrow[r];
  }
}

// ---------------------------------------------------------------------------
// Kernel 3: merge the 4 key-range splits: out = sum(O_i) / sum(l_i).
// ---------------------------------------------------------------------------
__global__ __launch_bounds__(256) void merge_splits(
    const unsigned short* __restrict__ Op, const float* __restrict__ lsum,
    float* __restrict__ out) {
  int idx = blockIdx.x * 256 + threadIdx.x;
  int row = idx >> 4;
  int h4 = (idx & 15) * 4;
  int b = row >> 11, t = row & 2047;
  int qt = t >> 6, r = t & 63;
  float O0 = 0.f, O1 = 0.f, O2 = 0.f, O3 = 0.f, l = 0.f;
#pragma unroll
  for (int s = 0; s < 4; ++s) {
    size_t p = (((size_t)s * 8 + b) * 32 + qt) * 64 + r;
    l += lsum[p];
    ushort4 ov = *(const ushort4*)&Op[p * 64 + h4];
    O0 += bf2f(ov.x); O1 += bf2f(ov.y); O2 += bf2f(ov.z); O3 += bf2f(ov.w);
  }
  float inv = 1.0f / l;
  float4 res = make_float4(O0 * inv, O1 * inv, O2 * inv, O3 * inv);
  *(float4*)&out[(size_t)row * H_ + h4] = res;
}

extern "C" void kernel_launch(void* const* d_in, const int* in_sizes, int n_in,
                              void* d_out, int out_size, void* d_ws, size_t ws_size,
                              hipStream_t stream) {
  const float* x  = (const float*)d_in[0];
  const float* wq = (const float*)d_in[1];
  const float* wk = (const float*)d_in[2];
  const float* wv = (const float*)d_in[3];
  float* out = (float*)d_out;

  char* ws = (char*)d_ws;
  unsigned short* wf = (unsigned short*)ws;                    // 393216 B
  unsigned short* qb = (unsigned short*)(ws + 393216);         // 2097152 B
  unsigned short* kf = (unsigned short*)(ws + 2490368);        // 2097152 B (frag-ready)
  unsigned short* vf = (unsigned short*)(ws + 4587520);        // 2097152 B (frag-ready)
  unsigned short* Op = (unsigned short*)(ws + 6684672);        // 8388608 B (4 splits)
  float*          ls = (float*)(ws + 15073280);                // 262144 B (total 15335424)

  conv_w<<<96, 256, 0, stream>>>(wq, wk, wv, wf);
  qkv_proj<<<512, 256, 0, stream>>>(x, wf, qb, kf, vf);
  attn<<<dim3(32, 8, 4), 256, 0, stream>>>(qb, kf, vf, Op, ls);
  merge_splits<<<1024, 256, 0, stream>>>(Op, ls, out);
}

// Round 14
// 128.933 us; speedup vs baseline: 1.1267x; 1.0293x over previous
//
#include <hip/hip_runtime.h>

#define B_ 8
#define T_ 2048
#define C_ 1024
#define H_ 64

typedef __attribute__((ext_vector_type(8))) short short8;
typedef __attribute__((ext_vector_type(4))) float floatx4;
typedef __attribute__((ext_vector_type(4))) int intx4;

static __device__ __forceinline__ unsigned short f2bf(float f) {
  unsigned int u = __builtin_bit_cast(unsigned int, f);
  u += 0x7FFFu + ((u >> 16) & 1u);   // RNE
  return (unsigned short)(u >> 16);
}
static __device__ __forceinline__ unsigned short f2bf_t(float f) {   // truncate
  return (unsigned short)(__builtin_bit_cast(unsigned int, f) >> 16);
}
static __device__ __forceinline__ float bf2f(unsigned short u) {
  return __builtin_bit_cast(float, ((unsigned int)u) << 16);
}
static __device__ __forceinline__ unsigned int fbits(float f) {
  return __builtin_bit_cast(unsigned int, f);
}

typedef const __attribute__((address_space(1))) unsigned int* gp1_t;
typedef __attribute__((address_space(3))) unsigned int* lp3_t;
static __device__ __forceinline__ void gl_lds16(const void* g, void* l) {
  __builtin_amdgcn_global_load_lds((gp1_t)g, (lp3_t)l, 16, 0, 0);
}

// ---------------------------------------------------------------------------
// Kernel 0: W fp32 -> Wf FRAGMENT-READY bf16 (unchanged).
// ---------------------------------------------------------------------------
__global__ __launch_bounds__(256) void conv_w(const float* __restrict__ wq,
    const float* __restrict__ wk, const float* __restrict__ wv,
    unsigned short* __restrict__ wf) {
  int c = blockIdx.x * 256 + threadIdx.x;   // 24576 chunks
  int lane = c & 63;
  int t = c >> 6;
  int ng = t % 12;
  int kk = t / 12;                           // kt*2+ks, 0..31
  int k0 = kk * 32 + (lane >> 4) * 8;
  int n = ng * 16 + (lane & 15);
  const float* src;
  int col;
  float scale = 1.0f;
  if (n < 64)       { src = wq; col = n;       scale = 0.03125f * 1.44269504088896340736f; }
  else if (n < 128) { src = wk; col = n - 64;  }
  else              { src = wv; col = n - 128; }
  unsigned short o[8];
#pragma unroll
  for (int j = 0; j < 8; ++j) o[j] = f2bf(src[(size_t)(k0 + j) * H_ + col] * scale);
  *(uint4*)&wf[(size_t)c * 8] = *(const uint4*)o;
}

// ---------------------------------------------------------------------------
// Kernel 1: QKV projection, DOUBLE-BUFFERED 8-phase staging + K-ROTATION.
// Grid 512 (32-row tiles), 4 waves, 2 x 16 KB LDS -> 4 blocks/CU.
// R13 flaws fixed: (1) staging was issued after the barrier and compute
// immediately waited on it -- no prefetch overlap; now stage(ph+1) issues
// BEFORE compute(ph) (R4/R5 verified pattern). (2) all blocks swept Wf in
// the same ks order, hotspotting a 12 KB window of L2 each step; now each
// block starts its phase sequence at (blockIdx & 7) and wraps, spreading
// concurrent reads over the full 384 KB (K-sum is order-invariant).
// Phase = 32 rows x 128 fp32 (16 KB). bf16 convert at read via v_perm.
// XOR swizzle keeps unpadded LDS reads conflict-free (2-way, free).
// ---------------------------------------------------------------------------
__global__ __launch_bounds__(256, 4) void qkv_proj(
    const float* __restrict__ x, const unsigned short* __restrict__ wf,
    unsigned short* __restrict__ qo, unsigned short* __restrict__ kf,
    unsigned short* __restrict__ vf) {
  __shared__ float XL[2][4096];   // 2 x (32 rows x 128 fp32) = 32 KB
  int tid = threadIdx.x;
  int wave = tid >> 6, lane = tid & 63;
  int lane4 = lane & 15, quad = lane >> 4;
  int m0 = blockIdx.x * 32;
  int ph0 = blockIdx.x & 7;       // per-block K-order rotation

  // stage one phase (32 rows x 128 floats = 1024 16B-chunks, 4 insts/thread)
  auto stage_ph = [&](int phr, int buf) {
#pragma unroll
    for (int j = 0; j < 4; ++j) {
      int c = (wave * 4 + j) * 64 + lane;    // chunk id 0..1023
      int r = c >> 5, pc = c & 31;           // 32 chunks per row
      int cl = (pc & ~7) | ((pc ^ (r & 7)) & 7);
      gl_lds16(&x[(size_t)(m0 + r) * C_ + phr * 128 + cl * 4], &XL[buf][c * 4]);
    }
  };

  floatx4 acc[2][3];
#pragma unroll
  for (int mt = 0; mt < 2; ++mt)
#pragma unroll
    for (int nt = 0; nt < 3; ++nt) acc[mt][nt] = (floatx4)0.0f;

  stage_ph(ph0, 0);
  __syncthreads();

  for (int ph = 0; ph < 8; ++ph) {
    int buf = ph & 1;
    if (ph < 7) stage_ph((ph + 1 + ph0) & 7, buf ^ 1);   // async prefetch
    int phr = (ph + ph0) & 7;
#pragma unroll
    for (int sl = 0; sl < 4; ++sl) {
      int s = phr * 4 + sl;            // global ks-step, 0..31
      short8 b[3];
#pragma unroll
      for (int nt = 0; nt < 3; ++nt)
        b[nt] = *(const short8*)&wf[(size_t)(s * 12 + wave * 3 + nt) * 512 + lane * 8];
      short8 a[2];
#pragma unroll
      for (int mt = 0; mt < 2; ++mt) {
        int r = mt * 16 + lane4;
        int c0 = sl * 8 + quad * 2;    // phase-local float4-chunk, 0..31
        int pc0 = (c0 & ~7) | ((c0 ^ (r & 7)) & 7);
        int pc1 = ((c0 + 1) & ~7) | (((c0 + 1) ^ (r & 7)) & 7);
        float4 f0 = *(const float4*)&XL[buf][r * 128 + pc0 * 4];
        float4 f1 = *(const float4*)&XL[buf][r * 128 + pc1 * 4];
        intx4 pk;
        pk[0] = (int)__builtin_amdgcn_perm(fbits(f0.y), fbits(f0.x), 0x07060302u);
        pk[1] = (int)__builtin_amdgcn_perm(fbits(f0.w), fbits(f0.z), 0x07060302u);
        pk[2] = (int)__builtin_amdgcn_perm(fbits(f1.y), fbits(f1.x), 0x07060302u);
        pk[3] = (int)__builtin_amdgcn_perm(fbits(f1.w), fbits(f1.z), 0x07060302u);
        a[mt] = __builtin_bit_cast(short8, pk);
      }
#pragma unroll
      for (int mt = 0; mt < 2; ++mt)
#pragma unroll
        for (int nt = 0; nt < 3; ++nt)
          acc[mt][nt] = __builtin_amdgcn_mfma_f32_16x16x32_bf16(a[mt], b[nt], acc[mt][nt], 0, 0, 0);
    }
    __syncthreads();   // prefetch landed + all waves done with buf
  }

  // ---- epilogue: q direct; K,V via LDS into fragment-ready layouts ----
  unsigned short* VTB = (unsigned short*)&XL[0][0];   // [64 h][40] bf16 (V^T)
  unsigned short* KB  = VTB + 5120;                   // [32 t][72] bf16
#pragma unroll
  for (int mt = 0; mt < 2; ++mt)
#pragma unroll
    for (int nt = 0; nt < 3; ++nt) {
      int n = wave * 48 + nt * 16 + lane4;
#pragma unroll
      for (int rr = 0; rr < 4; ++rr) {
        unsigned short val = f2bf(acc[mt][nt][rr]);
        int lrow = mt * 16 + quad * 4 + rr;
        if (n < 64)       qo[(size_t)(m0 + lrow) * H_ + n] = val;
        else if (n < 128) KB[lrow * 72 + (n - 64)] = val;
        else              VTB[(n - 128) * 40 + lrow] = val;
      }
    }
  __syncthreads();
  {
    int bb = m0 >> 11, t0 = m0 & 2047;
    int st = t0 >> 6, off = t0 & 63;
    // K: 256 chunks (ks x ctl x 64 lanes)
    int ks = tid >> 7, ctl = (tid >> 6) & 1, ln = tid & 63;
    int ct = (off >> 4) + ctl;
    int tl = ctl * 16 + (ln & 15);
    int h0 = ks * 32 + (ln >> 4) * 8;
    uint4 kd = *(const uint4*)&KB[tl * 72 + h0];
    *(uint4*)&kf[((size_t)((bb * 32 + st) * 2 + ks) * 4 + ct) * 512 + ln * 8] = kd;
    // V: 256 chunks (nt x 64 lanes), ks fixed = off>>5
    int nt = tid >> 6, l4 = tid & 15, qs = (tid >> 4) & 3;
    int ksv = off >> 5;
    uint4 vd = *(const uint4*)&VTB[(nt * 16 + l4) * 40 + qs * 8];
    *(uint4*)&vf[((size_t)((bb * 32 + st) * 2 + ksv) * 4 + nt) * 512 + (tid & 63) * 8] = vd;
  }
}

// ---------------------------------------------------------------------------
// Kernel 2: causal flash attention, barrier-free, split-4, fixed-max softmax
// (m=8, base-2 scale folded into Wq). Unchanged from round 7.
// ---------------------------------------------------------------------------
__global__ __launch_bounds__(256) void attn(
    const unsigned short* __restrict__ qi, const unsigned short* __restrict__ Kf,
    const unsigned short* __restrict__ Vf, unsigned short* __restrict__ Op,
    float* __restrict__ lsum) {
  __shared__ unsigned short PL[4][16][72];

  int tid = threadIdx.x;
  int wave = tid >> 6, lane = tid & 63;
  int lane4 = lane & 15, quad = lane >> 4;
  int qt = 31 - (int)blockIdx.x;   // biggest blocks dispatch first
  int b = blockIdx.y, split = blockIdx.z;
  int qb = qt * 64;
  int base = b * T_;

  int ntile = qt + 1;
  int sBeg = (split * ntile) >> 2;
  int sEnd = ((split + 1) * ntile) >> 2;

  short8 aq[2];
#pragma unroll
  for (int ks = 0; ks < 2; ++ks)
    aq[ks] = *(const short8*)&qi[(size_t)(base + qb + wave * 16 + lane4) * H_ + ks * 32 + quad * 8];

  float lrow[4];
  floatx4 o[4];
#pragma unroll
  for (int r = 0; r < 4; ++r) lrow[r] = 0.0f;
#pragma unroll
  for (int nt = 0; nt < 4; ++nt) o[nt] = (floatx4)0.0f;

  for (int st = sBeg; st < sEnd; ++st) {
    size_t tb = (size_t)(b * 32 + st) * 8;
    short8 bk[2][4], bv[2][4];
#pragma unroll
    for (int ks = 0; ks < 2; ++ks)
#pragma unroll
      for (int ct = 0; ct < 4; ++ct)
        bk[ks][ct] = *(const short8*)&Kf[(tb + ks * 4 + ct) * 512 + lane * 8];
#pragma unroll
    for (int ks = 0; ks < 2; ++ks)
#pragma unroll
      for (int nt = 0; nt < 4; ++nt)
        bv[ks][nt] = *(const short8*)&Vf[(tb + ks * 4 + nt) * 512 + lane * 8];

    floatx4 sacc[4];
#pragma unroll
    for (int ct = 0; ct < 4; ++ct) sacc[ct] = (floatx4)0.0f;
#pragma unroll
    for (int ks = 0; ks < 2; ++ks)
#pragma unroll
      for (int ct = 0; ct < 4; ++ct)
        sacc[ct] = __builtin_amdgcn_mfma_f32_16x16x32_bf16(aq[ks], bk[ks][ct], sacc[ct], 0, 0, 0);

    if (st == qt) {   // diagonal tile mask
#pragma unroll
      for (int ct = 0; ct < 4; ++ct)
#pragma unroll
        for (int r = 0; r < 4; ++r) {
          int qrow = wave * 16 + quad * 4 + r;
          int scol = ct * 16 + lane4;
          if (scol > qrow) sacc[ct][r] = -3.0e38f;
        }
    }

    // fixed-max softmax: p = exp2(s - 8)
#pragma unroll
    for (int ct = 0; ct < 4; ++ct)
#pragma unroll
      for (int r = 0; r < 4; ++r) {
        float p = exp2f(sacc[ct][r] - 8.0f);
        lrow[r] += p;
        PL[wave][quad * 4 + r][ct * 16 + lane4] = f2bf_t(p);
      }

    // O += P V  (PL write->read same-wave; lgkmcnt orders it)
#pragma unroll
    for (int ks = 0; ks < 2; ++ks) {
      short8 pa = *(const short8*)&PL[wave][lane4][ks * 32 + quad * 8];
#pragma unroll
      for (int nt = 0; nt < 4; ++nt)
        o[nt] = __builtin_amdgcn_mfma_f32_16x16x32_bf16(pa, bv[ks][nt], o[nt], 0, 0, 0);
    }
  }

  // epilogue: l-reduce across the 16 lanes of each quad-group
#pragma unroll
  for (int off = 1; off < 16; off <<= 1)
#pragma unroll
    for (int r = 0; r < 4; ++r) lrow[r] += __shfl_xor(lrow[r], off);

  size_t pbase = (((size_t)split * 8 + b) * 32 + qt) * 64;
#pragma unroll
  for (int r = 0; r < 4; ++r) {
    int row = wave * 16 + quad * 4 + r;
#pragma unroll
    for (int nt = 0; nt < 4; ++nt)
      Op[(pbase + row) * 64 + nt * 16 + lane4] = f2bf(o[nt][r]);
    if (lane4 == 0) lsum[pbase + row] = lrow[r];
  }
}

// ---------------------------------------------------------------------------
// Kernel 3: merge the 4 key-range splits: out = sum(O_i) / sum(l_i).
// ---------------------------------------------------------------------------
__global__ __launch_bounds__(256) void merge_splits(
    const unsigned short* __restrict__ Op, const float* __restrict__ lsum,
    float* __restrict__ out) {
  int idx = blockIdx.x * 256 + threadIdx.x;
  int row = idx >> 4;
  int h4 = (idx & 15) * 4;
  int b = row >> 11, t = row & 2047;
  int qt = t >> 6, r = t & 63;
  float O0 = 0.f, O1 = 0.f, O2 = 0.f, O3 = 0.f, l = 0.f;
#pragma unroll
  for (int s = 0; s < 4; ++s) {
    size_t p = (((size_t)s * 8 + b) * 32 + qt) * 64 + r;
    l += lsum[p];
    ushort4 ov = *(const ushort4*)&Op[p * 64 + h4];
    O0 += bf2f(ov.x); O1 += bf2f(ov.y); O2 += bf2f(ov.z); O3 += bf2f(ov.w);
  }
  float inv = 1.0f / l;
  float4 res = make_float4(O0 * inv, O1 * inv, O2 * inv, O3 * inv);
  *(float4*)&out[(size_t)row * H_ + h4] = res;
}

extern "C" void kernel_launch(void* const* d_in, const int* in_sizes, int n_in,
                              void* d_out, int out_size, void* d_ws, size_t ws_size,
                              hipStream_t stream) {
  const float* x  = (const float*)d_in[0];
  const float* wq = (const float*)d_in[1];
  const float* wk = (const float*)d_in[2];
  const float* wv = (const float*)d_in[3];
  float* out = (float*)d_out;

  char* ws = (char*)d_ws;
  unsigned short* wf = (unsigned short*)ws;                    // 393216 B
  unsigned short* qb = (unsigned short*)(ws + 393216);         // 2097152 B
  unsigned short* kf = (unsigned short*)(ws + 2490368);        // 2097152 B (frag-ready)
  unsigned short* vf = (unsigned short*)(ws + 4587520);        // 2097152 B (frag-ready)
  unsigned short* Op = (unsigned short*)(ws + 6684672);        // 8388608 B (4 splits)
  float*          ls = (float*)(ws + 15073280);                // 262144 B (total 15335424)

  conv_w<<<96, 256, 0, stream>>>(wq, wk, wv, wf);
  qkv_proj<<<512, 256, 0, stream>>>(x, wf, qb, kf, vf);
  attn<<<dim3(32, 8, 4), 256, 0, stream>>>(qb, kf, vf, Op, ls);
  merge_splits<<<1024, 256, 0, stream>>>(Op, ls, out);
}